// Round 12
// baseline (477.805 us; speedup 1.0000x reference)
//
#include <hip/hip_runtime.h>
#include <math.h>

#define TPTS 200000
#define BB 2
#define NPTS (BB*TPTS)
#define GRID3 32768
#define BG 65536          // BB * GRID3
#define NMEGA (NPTS/64)   // 6250 mega blocks

typedef __attribute__((ext_vector_type(8))) __bf16 bf16x8;
typedef __attribute__((ext_vector_type(4))) float f32x4;
typedef unsigned short ushort_t;

#define MFMA16(a,b,c) __builtin_amdgcn_mfma_f32_16x16x32_bf16(a,b,c,0,0,0)

__device__ __forceinline__ void split8(const float* v, bf16x8& hi, bf16x8& lo)
{
#pragma unroll
  for (int j = 0; j < 8; j++) {
    float f = v[j];
    __bf16 h = (__bf16)f;
    hi[j] = h;
    lo[j] = (__bf16)(f - (float)h);   // exact residual, rounded to bf16
  }
}

// cell id: must match reference fp32 arithmetic exactly
__device__ __forceinline__ int cellof(float p0, float p1, float p2, int t)
{
  const float DEN = (float)(1.0 + 0.1 + 1e-3);
  const float HI  = (float)(1.0 - 1e-3);
  float n0 = fminf(fmaxf(p0/DEN + 0.5f, 0.f), HI);
  float n1 = fminf(fmaxf(p1/DEN + 0.5f, 0.f), HI);
  float n2 = fminf(fmaxf(p2/DEN + 0.5f, 0.f), HI);
  int c0 = (int)floorf(n0*32.f), c1 = (int)floorf(n1*32.f), c2 = (int)floorf(n2*32.f);
  return c0 + 32*(c1 + 32*c2) + (t >= TPTS ? GRID3 : 0);
}

__global__ __launch_bounds__(256) void k_hist(
    const float* __restrict__ p, int* __restrict__ gbuf, int* __restrict__ hist)
{
  int t = blockIdx.x*256 + threadIdx.x;
  if (t >= NPTS) return;
  int g = cellof(p[3*t], p[3*t+1], p[3*t+2], t);
  gbuf[t] = g;
  atomicAdd(hist + g, 1);
}

// 3-kernel parallel exclusive scan of hist[BG]
__global__ __launch_bounds__(256) void k_scanA(
    const int* __restrict__ hist, int* __restrict__ texcl, int* __restrict__ bsum)
{
  __shared__ int sm[256];
  int tid = threadIdx.x;
  int t = blockIdx.x*256 + tid;
  int v = hist[t];
  sm[tid] = v; __syncthreads();
  for (int off = 1; off < 256; off <<= 1) {
    int x = sm[tid];
    int u = (tid >= off) ? sm[tid-off] : 0;
    __syncthreads();
    sm[tid] = x + u;
    __syncthreads();
  }
  texcl[t] = sm[tid] - v;
  if (tid == 255) bsum[blockIdx.x] = sm[255];
}

__global__ __launch_bounds__(256) void k_scanB(
    const int* __restrict__ bsum, int* __restrict__ boff)
{
  __shared__ int sm[256];
  int tid = threadIdx.x;
  int v = bsum[tid];
  sm[tid] = v; __syncthreads();
  for (int off = 1; off < 256; off <<= 1) {
    int x = sm[tid];
    int u = (tid >= off) ? sm[tid-off] : 0;
    __syncthreads();
    sm[tid] = x + u;
    __syncthreads();
  }
  boff[tid] = sm[tid] - v;
}

__global__ __launch_bounds__(256) void k_scanC(
    const int* __restrict__ texcl, const int* __restrict__ boff,
    int* __restrict__ start, int* __restrict__ cursor)
{
  int t = blockIdx.x*256 + threadIdx.x;
  int v = boff[blockIdx.x] + texcl[t];
  start[t] = v; cursor[t] = v;
  if (t == 0) start[BG] = NPTS;
}

__global__ __launch_bounds__(256) void k_scatter(
    const float* __restrict__ p, const int* __restrict__ gbuf,
    int* __restrict__ cursor, float* __restrict__ p_sorted, int* __restrict__ gsort)
{
  int t = blockIdx.x*256 + threadIdx.x;
  if (t >= NPTS) return;
  int g = gbuf[t];
  int slot = atomicAdd(cursor + g, 1);
  gsort[slot] = g;
  p_sorted[3*slot]   = p[3*t];
  p_sorted[3*slot+1] = p[3*t+1];
  p_sorted[3*slot+2] = p[3*t+2];
}

// block boundaries at cell starts: blockA[k] = smallest cell-start >= 64k
__global__ __launch_bounds__(256) void k_blocks(
    const int* __restrict__ start, int* __restrict__ blockA)
{
  int k = blockIdx.x*256 + threadIdx.x;
  if (k > NMEGA) return;
  int t = k*64;
  int lo = 0, hi = BG;   // start[BG] = NPTS >= t always
  while (lo < hi) { int mid = (lo+hi) >> 1; if (start[mid] >= t) hi = mid; else lo = mid+1; }
  blockA[k] = start[lo];
}

// pack weights into MFMA B-fragment order (bf16 hi/lo), once.
// frags 0..99: resblock stages; 100..103: wc; 104..119: Wp (60x64, zero-padded K)
__global__ void k_pack(
    const float* __restrict__ f0w, const float* __restrict__ scw,
    const float* __restrict__ f1w, const float* __restrict__ wc,
    const float* __restrict__ Wp,
    ushort_t* __restrict__ wpack)
{
  int f = blockIdx.x, l = threadIdx.x;
  if (f >= 104) {
    int idx = f - 104;
    int c = idx >> 3, t = (idx >> 1) & 3, e = idx & 1;
#pragma unroll
    for (int j = 0; j < 8; j++) {
      int k = c*32 + (l>>4)*8 + j, n = t*16 + (l&15);
      float v = (k < 60) ? Wp[k*64 + n] : 0.f;
      __bf16 h = (__bf16)v;
      __bf16 out = (e == 0) ? h : (__bf16)(v - (float)h);
      union { __bf16 b; ushort_t u; } cv; cv.b = out;
      wpack[((size_t)f*64 + l)*8 + j] = cv.u;
    }
    return;
  }
  const float* W; int c, t, e;
  if (f < 100) {
    int s = f / 20, r = f % 20;
    if (r < 8)       { W = f0w + s*2048; c = r>>2;        t = (r>>1)&1; e = r&1; }
    else if (r < 16) { int q = r-8;  W = scw + s*2048; c = q>>2; t = (q>>1)&1; e = q&1; }
    else             { int q = r-16; W = f1w + s*1024; c = 0;    t = q>>1;     e = q&1; }
  } else { int q = f-100; W = wc; c = 0; t = q>>1; e = q&1; }
#pragma unroll
  for (int j = 0; j < 8; j++) {
    int k = c*32 + (l>>4)*8 + j, n = t*16 + (l&15);
    float v = W[k*32 + n];
    __bf16 h = (__bf16)v;
    __bf16 out = (e == 0) ? h : (__bf16)(v - (float)h);
    union { __bf16 b; ushort_t u; } cv; cv.b = out;
    wpack[((size_t)f*64 + l)*8 + j] = cv.u;
  }
}

// MEGA: whole network per block (block = whole cells, <=128 points).
// posenc -> fc_pos -> res0 -> [pool+res]x3 -> pool+res4+fc_c -> mean -> out.
// act double-buffered in LDS; zero intermediate HBM traffic.
__global__ __launch_bounds__(256) void k_mega(
    const float* __restrict__ ps, const int* __restrict__ gsort,
    const int* __restrict__ start, const int* __restrict__ blockA,
    const ushort_t* __restrict__ wpack,
    const float* __restrict__ bp, const float* __restrict__ f0b,
    const float* __restrict__ f1b, const float* __restrict__ bc,
    float* __restrict__ outp)
{
  __shared__ __align__(16) float smem[4608*2 + 4*576];   // actA, actB, hb = 46 KB
  float* actA = smem;
  float* actB = smem + 4608;
  float* hbB  = smem + 9216;

  int tid = threadIdx.x;
  int s = blockA[blockIdx.x], e = blockA[blockIdx.x + 1];
  int n = e - s;
  if (n <= 0) return;
  if (n > 128) n = 128;    // never expected (maxcell << 64)

  int wave = tid >> 6, lane = tid & 63;
  int m = lane & 15, q = lane >> 4;
  float* hb = hbB + wave*576;
  const float PIF = 3.14159265358979323846f;

  // per-chunk own-point info (constant-indexed, fully unrolled users)
  int ptc[2], rown[2], cs[2], ce[2];
#pragma unroll
  for (int c = 0; c < 2; c++) {
    int pt = s + c*64 + wave*16 + m;
    int pc = pt < e ? pt : (e-1);
    ptc[c] = pc; rown[c] = pc - s;
    int g = gsort[pc];
    cs[c] = start[g] - s; ce[c] = start[g+1] - s;
  }

  // ---------------- stage 0: PE -> fc_pos -> resblock0 -> actA ----------------
  {
    const ushort_t* wp0 = wpack;
    const ushort_t* wpPE = wpack + (size_t)104*512;
    bf16x8 w0f[2][2][2], wsf[2][2][2], w1f[2][2];
#pragma unroll
    for (int c = 0; c < 2; c++)
#pragma unroll
      for (int t = 0; t < 2; t++)
#pragma unroll
        for (int e2 = 0; e2 < 2; e2++) {
          w0f[c][t][e2] = *(const bf16x8*)(wp0 + ((size_t)(((c*2+t)*2+e2)    )*64 + lane)*8);
          wsf[c][t][e2] = *(const bf16x8*)(wp0 + ((size_t)(((c*2+t)*2+e2) + 8)*64 + lane)*8);
        }
#pragma unroll
    for (int t = 0; t < 2; t++)
#pragma unroll
      for (int e2 = 0; e2 < 2; e2++)
        w1f[t][e2] = *(const bf16x8*)(wp0 + ((size_t)(16 + t*2 + e2)*64 + lane)*8);

#pragma unroll
    for (int c = 0; c < 2; c++) {
      if (c*64 >= n) continue;           // block-uniform
      int pc = ptc[c];
      float p0 = ps[3*pc], p1 = ps[3*pc+1], p2 = ps[3*pc+2];
      float u0 = 2.f*p0 - 1.f, u1 = 2.f*p1 - 1.f, u2 = 2.f*p2 - 1.f;
      float pe[2][8];
#pragma unroll
      for (int c2 = 0; c2 < 2; c2++)
#pragma unroll
        for (int jj = 0; jj < 8; jj++) {
          int e1 = c2*32 + q*8 + jj;
          int l = (e1 * 43691) >> 18;    // e1 / 6
          int r = e1 - l*6;
          bool issin = (r < 3);
          int d = issin ? r : (r - 3);
          float ud = (d == 0) ? u0 : ((d == 1) ? u1 : u2);
          float xval = ldexpf(ud, l);                  // exact *2^l
          float red = xval - 2.f*rintf(0.5f*xval);     // exact mod-2
          float sv, cv;
          __sincosf(PIF*red, &sv, &cv);
          float v = issin ? sv : cv;
          pe[c2][jj] = (e1 < 60) ? v : 0.f;            // zero-pad K 60->64
        }
      bf16x8 peh[2], pel[2];
      split8(pe[0], peh[0], pel[0]);
      split8(pe[1], peh[1], pel[1]);

      f32x4 xacc[4];
#pragma unroll
      for (int t = 0; t < 4; t++) {
        float bb = bp[t*16 + m];
        xacc[t] = (f32x4){bb,bb,bb,bb};
      }
#pragma unroll
      for (int c2 = 0; c2 < 2; c2++)
#pragma unroll
        for (int t = 0; t < 4; t++) {
          bf16x8 bh = *(const bf16x8*)(wpPE + ((size_t)((c2*4+t)*2    )*64 + lane)*8);
          bf16x8 bl = *(const bf16x8*)(wpPE + ((size_t)((c2*4+t)*2 + 1)*64 + lane)*8);
          xacc[t] = MFMA16(peh[c2], bh, xacc[t]);
          xacc[t] = MFMA16(pel[c2], bh, xacc[t]);
          xacc[t] = MFMA16(peh[c2], bl, xacc[t]);
        }

      // x D-layout -> A-layout via actB scratch (stride 68, per-wave region)
      float* xl = actB + wave*1088;
#pragma unroll
      for (int t = 0; t < 4; t++)
#pragma unroll
        for (int r = 0; r < 4; r++)
          xl[(q*4+r)*68 + t*16 + m] = xacc[t][r];
      __syncthreads();
      float xv[2][8];
#pragma unroll
      for (int c2 = 0; c2 < 2; c2++)
#pragma unroll
        for (int jj = 0; jj < 8; jj++)
          xv[c2][jj] = xl[m*68 + c2*32 + q*8 + jj];
      __syncthreads();

      bf16x8 axh[2], axl[2], arh[2], arl[2];
#pragma unroll
      for (int c2 = 0; c2 < 2; c2++) {
        float r[8];
#pragma unroll
        for (int j = 0; j < 8; j++) r[j] = fmaxf(xv[c2][j], 0.f);
        split8(xv[c2], axh[c2], axl[c2]);
        split8(r,      arh[c2], arl[c2]);
      }
      f32x4 hacc[2], yacc[2];
#pragma unroll
      for (int t = 0; t < 2; t++) {
        float bb0 = f0b[m + 16*t], bb1 = f1b[m + 16*t];
        hacc[t] = (f32x4){bb0,bb0,bb0,bb0};
        yacc[t] = (f32x4){bb1,bb1,bb1,bb1};
      }
#pragma unroll
      for (int c2 = 0; c2 < 2; c2++)
#pragma unroll
        for (int t = 0; t < 2; t++) {
          hacc[t] = MFMA16(arh[c2], w0f[c2][t][0], hacc[t]);
          hacc[t] = MFMA16(arl[c2], w0f[c2][t][0], hacc[t]);
          hacc[t] = MFMA16(arh[c2], w0f[c2][t][1], hacc[t]);
          yacc[t] = MFMA16(axh[c2], wsf[c2][t][0], yacc[t]);
          yacc[t] = MFMA16(axl[c2], wsf[c2][t][0], yacc[t]);
          yacc[t] = MFMA16(axh[c2], wsf[c2][t][1], yacc[t]);
        }
#pragma unroll
      for (int t = 0; t < 2; t++)
#pragma unroll
        for (int r = 0; r < 4; r++)
          hb[(q*4+r)*36 + m + 16*t] = fmaxf(hacc[t][r], 0.f);
      __syncthreads();
      float hv[8];
#pragma unroll
      for (int j = 0; j < 8; j++) hv[j] = hb[m*36 + q*8 + j];
      __syncthreads();
      bf16x8 hh, hl; split8(hv, hh, hl);
#pragma unroll
      for (int t = 0; t < 2; t++) {
        yacc[t] = MFMA16(hh, w1f[t][0], yacc[t]);
        yacc[t] = MFMA16(hl, w1f[t][0], yacc[t]);
        yacc[t] = MFMA16(hh, w1f[t][1], yacc[t]);
      }
#pragma unroll
      for (int t = 0; t < 2; t++)
#pragma unroll
        for (int r = 0; r < 4; r++) {
          int prow = c*64 + wave*16 + q*4 + r;
          if (prow < n) actA[prow*36 + m + 16*t] = yacc[t][r];
        }
      __syncthreads();
    }
  }
  __syncthreads();

  // ---------------- stages 1..4 ----------------
  for (int st = 1; st <= 4; st++) {
    const float* bin = (st & 1) ? actA : actB;
    float* bout = (st & 1) ? actB : actA;
    bool last = (st == 4);
    const ushort_t* wp = wpack + (size_t)st*20*512;
    const float* b0 = f0b + st*32;
    const float* b1 = f1b + st*32;

    bf16x8 w0f[2][2][2], wsf[2][2][2], w1f[2][2], wcf[2][2];
#pragma unroll
    for (int c = 0; c < 2; c++)
#pragma unroll
      for (int t = 0; t < 2; t++)
#pragma unroll
        for (int e2 = 0; e2 < 2; e2++) {
          w0f[c][t][e2] = *(const bf16x8*)(wp + ((size_t)(((c*2+t)*2+e2)    )*64 + lane)*8);
          wsf[c][t][e2] = *(const bf16x8*)(wp + ((size_t)(((c*2+t)*2+e2) + 8)*64 + lane)*8);
        }
#pragma unroll
    for (int t = 0; t < 2; t++)
#pragma unroll
      for (int e2 = 0; e2 < 2; e2++) {
        w1f[t][e2] = *(const bf16x8*)(wp + ((size_t)(16 + t*2 + e2)*64 + lane)*8);
        wcf[t][e2] = *(const bf16x8*)(wpack + ((size_t)(100 + t*2 + e2)*64 + lane)*8);
      }

#pragma unroll
    for (int c = 0; c < 2; c++) {
      if (c*64 >= n) continue;           // block-uniform
      float xv[2][8];
      {
        const float* xr = bin + rown[c]*36 + q*8;
        *(f32x4*)&xv[0][0] = *(const f32x4*)xr;
        *(f32x4*)&xv[0][4] = *(const f32x4*)(xr + 4);
      }
      {
        f32x4 ma = (f32x4){-INFINITY,-INFINITY,-INFINITY,-INFINITY};
        f32x4 mb = ma;
        for (int k = cs[c]; k < ce[c]; k++) {
          const float* rr = bin + k*36 + q*8;
          f32x4 va = *(const f32x4*)rr;
          f32x4 vb = *(const f32x4*)(rr + 4);
          ma.x = fmaxf(ma.x, va.x); ma.y = fmaxf(ma.y, va.y);
          ma.z = fmaxf(ma.z, va.z); ma.w = fmaxf(ma.w, va.w);
          mb.x = fmaxf(mb.x, vb.x); mb.y = fmaxf(mb.y, vb.y);
          mb.z = fmaxf(mb.z, vb.z); mb.w = fmaxf(mb.w, vb.w);
        }
        *(f32x4*)&xv[1][0] = ma;
        *(f32x4*)&xv[1][4] = mb;
      }

      bf16x8 axh[2], axl[2], arh[2], arl[2];
#pragma unroll
      for (int c2 = 0; c2 < 2; c2++) {
        float r[8];
#pragma unroll
        for (int j = 0; j < 8; j++) r[j] = fmaxf(xv[c2][j], 0.f);
        split8(xv[c2], axh[c2], axl[c2]);
        split8(r,      arh[c2], arl[c2]);
      }
      f32x4 hacc[2], yacc[2];
#pragma unroll
      for (int t = 0; t < 2; t++) {
        float bb0 = b0[m + 16*t], bb1 = b1[m + 16*t];
        hacc[t] = (f32x4){bb0,bb0,bb0,bb0};
        yacc[t] = (f32x4){bb1,bb1,bb1,bb1};
      }
#pragma unroll
      for (int c2 = 0; c2 < 2; c2++)
#pragma unroll
        for (int t = 0; t < 2; t++) {
          hacc[t] = MFMA16(arh[c2], w0f[c2][t][0], hacc[t]);
          hacc[t] = MFMA16(arl[c2], w0f[c2][t][0], hacc[t]);
          hacc[t] = MFMA16(arh[c2], w0f[c2][t][1], hacc[t]);
          yacc[t] = MFMA16(axh[c2], wsf[c2][t][0], yacc[t]);
          yacc[t] = MFMA16(axl[c2], wsf[c2][t][0], yacc[t]);
          yacc[t] = MFMA16(axh[c2], wsf[c2][t][1], yacc[t]);
        }
#pragma unroll
      for (int t = 0; t < 2; t++)
#pragma unroll
        for (int r = 0; r < 4; r++)
          hb[(q*4+r)*36 + m + 16*t] = fmaxf(hacc[t][r], 0.f);
      __syncthreads();
      float hv[8];
#pragma unroll
      for (int j = 0; j < 8; j++) hv[j] = hb[m*36 + q*8 + j];
      __syncthreads();
      bf16x8 hh, hl; split8(hv, hh, hl);
#pragma unroll
      for (int t = 0; t < 2; t++) {
        yacc[t] = MFMA16(hh, w1f[t][0], yacc[t]);
        yacc[t] = MFMA16(hl, w1f[t][0], yacc[t]);
        yacc[t] = MFMA16(hh, w1f[t][1], yacc[t]);
      }

      if (!last) {
#pragma unroll
        for (int t = 0; t < 2; t++)
#pragma unroll
          for (int r = 0; r < 4; r++) {
            int prow = c*64 + wave*16 + q*4 + r;
            if (prow < n) bout[prow*36 + m + 16*t] = yacc[t][r];
          }
      } else {
        // y -> A-layout -> fc_c
#pragma unroll
        for (int t = 0; t < 2; t++)
#pragma unroll
          for (int r = 0; r < 4; r++)
            hb[(q*4+r)*36 + m + 16*t] = yacc[t][r];
        __syncthreads();
        float yv[8];
#pragma unroll
        for (int j = 0; j < 8; j++) yv[j] = hb[m*36 + q*8 + j];
        __syncthreads();
        bf16x8 yh, yl; split8(yv, yh, yl);
        f32x4 cacc[2];
#pragma unroll
        for (int t = 0; t < 2; t++) {
          float bb = bc[m + 16*t];
          cacc[t] = (f32x4){bb,bb,bb,bb};
          cacc[t] = MFMA16(yh, wcf[t][0], cacc[t]);
          cacc[t] = MFMA16(yl, wcf[t][0], cacc[t]);
          cacc[t] = MFMA16(yh, wcf[t][1], cacc[t]);
        }
#pragma unroll
        for (int t = 0; t < 2; t++)
#pragma unroll
          for (int r = 0; r < 4; r++) {
            int prow = c*64 + wave*16 + q*4 + r;
            if (prow < n) bout[prow*36 + m + 16*t] = cacc[t][r];
          }
      }
      __syncthreads();
    }
    __syncthreads();
  }

  // ---------------- mean per cell -> out (leaders only) ----------------
  // st4 wrote actA. Leader = first point of its cell.
  for (int r = tid; r < n; r += 256) {
    int pt = s + r;
    int g = gsort[pt];
    int gs = start[g];
    if (gs != pt) continue;
    int ge = start[g+1];
    float inv = 1.f / (float)(ge - gs);
    int b = g >> 15, cell = g & 32767;
    size_t ob = ((size_t)b << 20) + cell;
#pragma unroll
    for (int sub = 0; sub < 8; sub++) {
      f32x4 sm = (f32x4){0.f,0.f,0.f,0.f};
      for (int rr = gs - s; rr < ge - s; rr++) {
        f32x4 v = *(const f32x4*)(actA + rr*36 + sub*4);
        sm.x += v.x; sm.y += v.y; sm.z += v.z; sm.w += v.w;
      }
#pragma unroll
      for (int j = 0; j < 4; j++)
        outp[ob + ((size_t)(sub*4 + j) << 15)] = ((float*)&sm)[j] * inv;
    }
  }
}

extern "C" void kernel_launch(void* const* d_in, const int* in_sizes, int n_in,
                              void* d_out, int out_size, void* d_ws, size_t ws_size,
                              hipStream_t stream)
{
  const float* p   = (const float*)d_in[0];
  const float* Wp  = (const float*)d_in[1];
  const float* bp  = (const float*)d_in[2];
  const float* f0w = (const float*)d_in[3];
  const float* f0b = (const float*)d_in[4];
  const float* f1w = (const float*)d_in[5];
  const float* f1b = (const float*)d_in[6];
  const float* scw = (const float*)d_in[7];
  const float* wc  = (const float*)d_in[8];
  const float* bc  = (const float*)d_in[9];
  float* outp = (float*)d_out;

  char* wsb = (char*)d_ws;
  int*      gbuf     = (int*)wsb;                         // NPTS
  int*      gsort    = gbuf + NPTS;                       // NPTS
  int*      hist     = gsort + NPTS;                      // BG
  int*      start    = hist + BG;                         // BG+1
  int*      cursor   = start + BG + 1;                    // BG
  int*      texcl    = cursor + BG;                       // BG
  int*      bsum     = texcl + BG;                        // 256
  int*      boff     = bsum + 256;                        // 256
  int*      blockA   = boff + 256;                        // NMEGA+1
  ushort_t* wpack    = (ushort_t*)(blockA + NMEGA + 1);   // 120*512 ushort
  float*    p_sorted = (float*)(wpack + (size_t)120*512); // NPTS*3

  dim3 blk(256);
  dim3 gpts((NPTS + 255)/256);
  dim3 gscan(BG/256);

  hipMemsetAsync(hist, 0, (size_t)BG*4, stream);
  hipMemsetAsync(outp, 0, (size_t)out_size*sizeof(float), stream);
  hipLaunchKernelGGL(k_hist, gpts, blk, 0, stream, p, gbuf, hist);
  hipLaunchKernelGGL(k_scanA, gscan, blk, 0, stream, hist, texcl, bsum);
  hipLaunchKernelGGL(k_scanB, dim3(1), blk, 0, stream, bsum, boff);
  hipLaunchKernelGGL(k_scanC, gscan, blk, 0, stream, texcl, boff, start, cursor);
  hipLaunchKernelGGL(k_scatter, gpts, blk, 0, stream, p, gbuf, cursor, p_sorted, gsort);
  hipLaunchKernelGGL(k_blocks, dim3((NMEGA + 256)/256), blk, 0, stream, start, blockA);
  hipLaunchKernelGGL(k_pack, dim3(120), dim3(64), 0, stream, f0w, scw, f1w, wc, Wp, wpack);
  hipLaunchKernelGGL(k_mega, dim3(NMEGA), blk, 0, stream,
                     p_sorted, gsort, start, blockA, wpack,
                     bp, f0b, f1b, bc, outp);
}

// Round 13
// 371.114 us; speedup vs baseline: 1.2875x; 1.2875x over previous
//
#include <hip/hip_runtime.h>
#include <math.h>

#define TPTS 200000
#define BB 2
#define NPTS (BB*TPTS)
#define GRID3 32768
#define BG 65536   // BB * GRID3
#define SROWS 176  // LDS staging rows per stage block (64 pts + cell overhang)
#define NMEGA (NPTS/64)

typedef __attribute__((ext_vector_type(8))) __bf16 bf16x8;
typedef __attribute__((ext_vector_type(4))) float f32x4;
typedef unsigned short ushort_t;

#define MFMA16(a,b,c) __builtin_amdgcn_mfma_f32_16x16x32_bf16(a,b,c,0,0,0)

__device__ __forceinline__ void split8(const float* v, bf16x8& hi, bf16x8& lo)
{
#pragma unroll
  for (int j = 0; j < 8; j++) {
    float f = v[j];
    __bf16 h = (__bf16)f;
    hi[j] = h;
    lo[j] = (__bf16)(f - (float)h);   // exact residual, rounded to bf16
  }
}

// cell id: must match reference fp32 arithmetic exactly
__device__ __forceinline__ int cellof(float p0, float p1, float p2, int t)
{
  const float DEN = (float)(1.0 + 0.1 + 1e-3);
  const float HI  = (float)(1.0 - 1e-3);
  float n0 = fminf(fmaxf(p0/DEN + 0.5f, 0.f), HI);
  float n1 = fminf(fmaxf(p1/DEN + 0.5f, 0.f), HI);
  float n2 = fminf(fmaxf(p2/DEN + 0.5f, 0.f), HI);
  int c0 = (int)floorf(n0*32.f), c1 = (int)floorf(n1*32.f), c2 = (int)floorf(n2*32.f);
  return c0 + 32*(c1 + 32*c2) + (t >= TPTS ? GRID3 : 0);
}

__global__ __launch_bounds__(256) void k_hist(
    const float* __restrict__ p, int* __restrict__ gbuf, int* __restrict__ hist)
{
  int t = blockIdx.x*256 + threadIdx.x;
  if (t >= NPTS) return;
  int g = cellof(p[3*t], p[3*t+1], p[3*t+2], t);
  gbuf[t] = g;
  atomicAdd(hist + g, 1);
}

// 3-kernel parallel exclusive scan of hist[BG]
__global__ __launch_bounds__(256) void k_scanA(
    const int* __restrict__ hist, int* __restrict__ texcl, int* __restrict__ bsum)
{
  __shared__ int sm[256];
  int tid = threadIdx.x;
  int t = blockIdx.x*256 + tid;
  int v = hist[t];
  sm[tid] = v; __syncthreads();
  for (int off = 1; off < 256; off <<= 1) {
    int x = sm[tid];
    int u = (tid >= off) ? sm[tid-off] : 0;
    __syncthreads();
    sm[tid] = x + u;
    __syncthreads();
  }
  texcl[t] = sm[tid] - v;
  if (tid == 255) bsum[blockIdx.x] = sm[255];
}

__global__ __launch_bounds__(256) void k_scanB(
    const int* __restrict__ bsum, int* __restrict__ boff)
{
  __shared__ int sm[256];
  int tid = threadIdx.x;
  int v = bsum[tid];
  sm[tid] = v; __syncthreads();
  for (int off = 1; off < 256; off <<= 1) {
    int x = sm[tid];
    int u = (tid >= off) ? sm[tid-off] : 0;
    __syncthreads();
    sm[tid] = x + u;
    __syncthreads();
  }
  boff[tid] = sm[tid] - v;
}

__global__ __launch_bounds__(256) void k_scanC(
    const int* __restrict__ texcl, const int* __restrict__ boff,
    int* __restrict__ start, int* __restrict__ cursor)
{
  int t = blockIdx.x*256 + threadIdx.x;
  int v = boff[blockIdx.x] + texcl[t];
  start[t] = v; cursor[t] = v;
  if (t == 0) start[BG] = NPTS;
}

__global__ __launch_bounds__(256) void k_scatter(
    const float* __restrict__ p, const int* __restrict__ gbuf,
    int* __restrict__ cursor, float* __restrict__ p_sorted, int* __restrict__ gsort)
{
  int t = blockIdx.x*256 + threadIdx.x;
  if (t >= NPTS) return;
  int g = gbuf[t];
  int slot = atomicAdd(cursor + g, 1);
  gsort[slot] = g;
  p_sorted[3*slot]   = p[3*t];
  p_sorted[3*slot+1] = p[3*t+1];
  p_sorted[3*slot+2] = p[3*t+2];
}

// block boundaries at cell starts: blockA[k] = smallest cell-start >= 64k
__global__ __launch_bounds__(256) void k_blocks(
    const int* __restrict__ start, int* __restrict__ blockA)
{
  int k = blockIdx.x*256 + threadIdx.x;
  if (k > NMEGA) return;
  int t = k*64;
  int lo = 0, hi = BG;
  while (lo < hi) { int mid = (lo+hi) >> 1; if (start[mid] >= t) hi = mid; else lo = mid+1; }
  blockA[k] = start[lo];
}

// pack weights into MFMA B-fragment order (bf16 hi/lo), once.
// frags 0..99: resblock stages; 100..103: wc; 104..119: Wp (60x64, zero-padded K)
__global__ void k_pack(
    const float* __restrict__ f0w, const float* __restrict__ scw,
    const float* __restrict__ f1w, const float* __restrict__ wc,
    const float* __restrict__ Wp,
    ushort_t* __restrict__ wpack)
{
  int f = blockIdx.x, l = threadIdx.x;
  if (f >= 104) {
    int idx = f - 104;
    int c = idx >> 3, t = (idx >> 1) & 3, e = idx & 1;
#pragma unroll
    for (int j = 0; j < 8; j++) {
      int k = c*32 + (l>>4)*8 + j, n = t*16 + (l&15);
      float v = (k < 60) ? Wp[k*64 + n] : 0.f;
      __bf16 h = (__bf16)v;
      __bf16 out = (e == 0) ? h : (__bf16)(v - (float)h);
      union { __bf16 b; ushort_t u; } cv; cv.b = out;
      wpack[((size_t)f*64 + l)*8 + j] = cv.u;
    }
    return;
  }
  const float* W; int c, t, e;
  if (f < 100) {
    int s = f / 20, r = f % 20;
    if (r < 8)       { W = f0w + s*2048; c = r>>2;        t = (r>>1)&1; e = r&1; }
    else if (r < 16) { int q = r-8;  W = scw + s*2048; c = q>>2; t = (q>>1)&1; e = q&1; }
    else             { int q = r-16; W = f1w + s*1024; c = 0;    t = q>>1;     e = q&1; }
  } else { int q = f-100; W = wc; c = 0; t = q>>1; e = q&1; }
#pragma unroll
  for (int j = 0; j < 8; j++) {
    int k = c*32 + (l>>4)*8 + j, n = t*16 + (l&15);
    float v = W[k*32 + n];
    __bf16 h = (__bf16)v;
    __bf16 out = (e == 0) ? h : (__bf16)(v - (float)h);
    union { __bf16 b; ushort_t u; } cv; cv.b = out;
    wpack[((size_t)f*64 + l)*8 + j] = cv.u;
  }
}

// FUSED: per-lane PE entries (A-frag layout) -> MFMA fc_pos -> LDS transpose
// -> MFMA resblock0 -> net AoS [pt][32].
__global__ __launch_bounds__(256) void k_fused0(
    const float* __restrict__ ps,
    const ushort_t* __restrict__ wpPE, const float* __restrict__ bp,
    const ushort_t* __restrict__ wp,
    const float* __restrict__ b0, const float* __restrict__ b1,
    float* __restrict__ net)
{
  __shared__ float xlds[4][16*68];
  __shared__ float hbuf[4][16*36];
  int wave = threadIdx.x >> 6, lane = threadIdx.x & 63;
  int m = lane & 15, q = lane >> 4;
  int pbase = (blockIdx.x*4 + wave)*16;
  int pt = pbase + m;

  float p0 = ps[3*pt], p1 = ps[3*pt+1], p2 = ps[3*pt+2];
  float u0 = 2.f*p0 - 1.f, u1 = 2.f*p1 - 1.f, u2 = 2.f*p2 - 1.f;
  const float PIF = 3.14159265358979323846f;

  float pe[2][8];
#pragma unroll
  for (int c2 = 0; c2 < 2; c2++) {
#pragma unroll
    for (int jj = 0; jj < 8; jj++) {
      int e = c2*32 + q*8 + jj;
      int l = (e * 43691) >> 18;         // e / 6
      int r = e - l*6;
      bool issin = (r < 3);
      int d = issin ? r : (r - 3);
      float ud = (d == 0) ? u0 : ((d == 1) ? u1 : u2);
      float xval = ldexpf(ud, l);                    // exact *2^l
      float red = xval - 2.f*rintf(0.5f*xval);       // exact mod-2
      float sv, cv;
      __sincosf(PIF*red, &sv, &cv);
      float v = issin ? sv : cv;
      pe[c2][jj] = (e < 60) ? v : 0.f;
    }
  }
  bf16x8 peh[2], pel[2];
  split8(pe[0], peh[0], pel[0]);
  split8(pe[1], peh[1], pel[1]);

  f32x4 xacc[4];
#pragma unroll
  for (int t = 0; t < 4; t++) {
    float bb = bp[t*16 + m];
    xacc[t] = (f32x4){bb,bb,bb,bb};
  }
#pragma unroll
  for (int c2 = 0; c2 < 2; c2++)
#pragma unroll
    for (int t = 0; t < 4; t++) {
      bf16x8 bh = *(const bf16x8*)(wpPE + ((size_t)((c2*4+t)*2    )*64 + lane)*8);
      bf16x8 bl = *(const bf16x8*)(wpPE + ((size_t)((c2*4+t)*2 + 1)*64 + lane)*8);
      xacc[t] = MFMA16(peh[c2], bh, xacc[t]);
      xacc[t] = MFMA16(pel[c2], bh, xacc[t]);
      xacc[t] = MFMA16(peh[c2], bl, xacc[t]);
    }

  float* xl = xlds[wave];
#pragma unroll
  for (int t = 0; t < 4; t++)
#pragma unroll
    for (int r = 0; r < 4; r++)
      xl[(q*4+r)*68 + t*16 + m] = xacc[t][r];
  __syncthreads();

  float xv[2][8];
#pragma unroll
  for (int c2 = 0; c2 < 2; c2++)
#pragma unroll
    for (int jj = 0; jj < 8; jj++)
      xv[c2][jj] = xl[m*68 + c2*32 + q*8 + jj];

  bf16x8 w0f[2][2][2], wsf[2][2][2], w1f[2][2];
#pragma unroll
  for (int c = 0; c < 2; c++)
#pragma unroll
    for (int t = 0; t < 2; t++)
#pragma unroll
      for (int e = 0; e < 2; e++) {
        w0f[c][t][e] = *(const bf16x8*)(wp + ((size_t)(((c*2+t)*2+e)    )*64 + lane)*8);
        wsf[c][t][e] = *(const bf16x8*)(wp + ((size_t)(((c*2+t)*2+e) + 8)*64 + lane)*8);
      }
#pragma unroll
  for (int t = 0; t < 2; t++)
#pragma unroll
    for (int e = 0; e < 2; e++)
      w1f[t][e] = *(const bf16x8*)(wp + ((size_t)(16 + t*2 + e)*64 + lane)*8);

  bf16x8 axh[2], axl[2], arh[2], arl[2];
#pragma unroll
  for (int c = 0; c < 2; c++) {
    float r[8];
#pragma unroll
    for (int j = 0; j < 8; j++) r[j] = fmaxf(xv[c][j], 0.f);
    split8(xv[c], axh[c], axl[c]);
    split8(r,     arh[c], arl[c]);
  }

  f32x4 hacc[2], yacc[2];
#pragma unroll
  for (int t = 0; t < 2; t++) {
    float bb0 = b0[m + 16*t], bb1 = b1[m + 16*t];
    hacc[t] = (f32x4){bb0,bb0,bb0,bb0};
    yacc[t] = (f32x4){bb1,bb1,bb1,bb1};
  }

#pragma unroll
  for (int c = 0; c < 2; c++)
#pragma unroll
    for (int t = 0; t < 2; t++) {
      hacc[t] = MFMA16(arh[c], w0f[c][t][0], hacc[t]);
      hacc[t] = MFMA16(arl[c], w0f[c][t][0], hacc[t]);
      hacc[t] = MFMA16(arh[c], w0f[c][t][1], hacc[t]);
      yacc[t] = MFMA16(axh[c], wsf[c][t][0], yacc[t]);
      yacc[t] = MFMA16(axl[c], wsf[c][t][0], yacc[t]);
      yacc[t] = MFMA16(axh[c], wsf[c][t][1], yacc[t]);
    }

  float* hb = hbuf[wave];
#pragma unroll
  for (int t = 0; t < 2; t++)
#pragma unroll
    for (int r = 0; r < 4; r++)
      hb[(q*4+r)*36 + m + 16*t] = fmaxf(hacc[t][r], 0.f);
  __syncthreads();
  float hv[8];
#pragma unroll
  for (int j = 0; j < 8; j++) hv[j] = hb[m*36 + q*8 + j];
  bf16x8 hh, hl; split8(hv, hh, hl);
#pragma unroll
  for (int t = 0; t < 2; t++) {
    yacc[t] = MFMA16(hh, w1f[t][0], yacc[t]);
    yacc[t] = MFMA16(hl, w1f[t][0], yacc[t]);
    yacc[t] = MFMA16(hh, w1f[t][1], yacc[t]);
  }

#pragma unroll
  for (int t = 0; t < 2; t++)
#pragma unroll
    for (int r = 0; r < 4; r++)
      net[(size_t)(pbase + q*4 + r)*32 + m + 16*t] = yacc[t][r];
}

// FUSED pool+stage: stage netin rows [s,e) in LDS, cell-max locally,
// resblock via MFMA -> netout. Point-aligned blocks (64 pts).
__global__ __launch_bounds__(256) void k_stage_f(
    const float* __restrict__ netin, float* __restrict__ netout,
    const int* __restrict__ gsort, const int* __restrict__ start,
    const ushort_t* __restrict__ wp,
    const float* __restrict__ b0, const float* __restrict__ b1)
{
  __shared__ float sbuf[SROWS*36];
  int tid = threadIdx.x;
  int P0 = blockIdx.x*64;
  int s = start[gsort[P0]];
  int e = start[gsort[P0+63] + 1];
  int n = e - s; if (n > SROWS) n = SROWS;

  for (int idx = tid; idx < n*8; idx += 256) {
    int r = idx >> 3, c = idx & 7;
    *(f32x4*)(sbuf + r*36 + c*4) =
      *(const f32x4*)(netin + ((size_t)(s + r))*32 + c*4);
  }
  __syncthreads();

  int wave = tid >> 6, lane = tid & 63;
  int m = lane & 15, q = lane >> 4;
  int pbase = P0 + wave*16;
  int pt = pbase + m;
  int g = gsort[pt];
  int cs = start[g] - s, ce = start[g+1] - s;

  float xv[2][8];
  {
    const float* xr = sbuf + (pt - s)*36 + q*8;
    *(f32x4*)&xv[0][0] = *(const f32x4*)xr;
    *(f32x4*)&xv[0][4] = *(const f32x4*)(xr + 4);
  }
  {
    f32x4 ma = (f32x4){-INFINITY,-INFINITY,-INFINITY,-INFINITY};
    f32x4 mb = ma;
    for (int k = cs; k < ce; k++) {
      const float* rr = sbuf + k*36 + q*8;
      f32x4 va = *(const f32x4*)rr;
      f32x4 vb = *(const f32x4*)(rr + 4);
      ma.x = fmaxf(ma.x, va.x); ma.y = fmaxf(ma.y, va.y);
      ma.z = fmaxf(ma.z, va.z); ma.w = fmaxf(ma.w, va.w);
      mb.x = fmaxf(mb.x, vb.x); mb.y = fmaxf(mb.y, vb.y);
      mb.z = fmaxf(mb.z, vb.z); mb.w = fmaxf(mb.w, vb.w);
    }
    *(f32x4*)&xv[1][0] = ma;
    *(f32x4*)&xv[1][4] = mb;
  }

  bf16x8 w0f[2][2][2], wsf[2][2][2], w1f[2][2];
#pragma unroll
  for (int c = 0; c < 2; c++)
#pragma unroll
    for (int t = 0; t < 2; t++)
#pragma unroll
      for (int e2 = 0; e2 < 2; e2++) {
        w0f[c][t][e2] = *(const bf16x8*)(wp + ((size_t)(((c*2+t)*2+e2)    )*64 + lane)*8);
        wsf[c][t][e2] = *(const bf16x8*)(wp + ((size_t)(((c*2+t)*2+e2) + 8)*64 + lane)*8);
      }
#pragma unroll
  for (int t = 0; t < 2; t++)
#pragma unroll
    for (int e2 = 0; e2 < 2; e2++)
      w1f[t][e2] = *(const bf16x8*)(wp + ((size_t)(16 + t*2 + e2)*64 + lane)*8);

  bf16x8 axh[2], axl[2], arh[2], arl[2];
#pragma unroll
  for (int c = 0; c < 2; c++) {
    float r[8];
#pragma unroll
    for (int j = 0; j < 8; j++) r[j] = fmaxf(xv[c][j], 0.f);
    split8(xv[c], axh[c], axl[c]);
    split8(r,     arh[c], arl[c]);
  }

  f32x4 hacc[2], yacc[2];
#pragma unroll
  for (int t = 0; t < 2; t++) {
    float bb0 = b0[m + 16*t], bb1 = b1[m + 16*t];
    hacc[t] = (f32x4){bb0,bb0,bb0,bb0};
    yacc[t] = (f32x4){bb1,bb1,bb1,bb1};
  }

#pragma unroll
  for (int c = 0; c < 2; c++)
#pragma unroll
    for (int t = 0; t < 2; t++) {
      hacc[t] = MFMA16(arh[c], w0f[c][t][0], hacc[t]);
      hacc[t] = MFMA16(arl[c], w0f[c][t][0], hacc[t]);
      hacc[t] = MFMA16(arh[c], w0f[c][t][1], hacc[t]);
      yacc[t] = MFMA16(axh[c], wsf[c][t][0], yacc[t]);
      yacc[t] = MFMA16(axl[c], wsf[c][t][0], yacc[t]);
      yacc[t] = MFMA16(axh[c], wsf[c][t][1], yacc[t]);
    }

  __syncthreads();
  float* hb = sbuf + wave*576;
#pragma unroll
  for (int t = 0; t < 2; t++)
#pragma unroll
    for (int r = 0; r < 4; r++)
      hb[(q*4+r)*36 + m + 16*t] = fmaxf(hacc[t][r], 0.f);
  __syncthreads();
  float hv[8];
#pragma unroll
  for (int j = 0; j < 8; j++) hv[j] = hb[m*36 + q*8 + j];
  bf16x8 hh, hl; split8(hv, hh, hl);
#pragma unroll
  for (int t = 0; t < 2; t++) {
    yacc[t] = MFMA16(hh, w1f[t][0], yacc[t]);
    yacc[t] = MFMA16(hl, w1f[t][0], yacc[t]);
    yacc[t] = MFMA16(hh, w1f[t][1], yacc[t]);
  }

#pragma unroll
  for (int t = 0; t < 2; t++)
#pragma unroll
    for (int r = 0; r < 4; r++)
      netout[(size_t)(pbase + q*4 + r)*32 + m + 16*t] = yacc[t][r];
}

// FUSED pool+final+fc_c+MEAN: cell-aligned blocks; writes outp directly.
__global__ __launch_bounds__(256) void k_finalmean(
    const float* __restrict__ netin, const int* __restrict__ gsort,
    const int* __restrict__ start, const int* __restrict__ blockA,
    const ushort_t* __restrict__ wp, const ushort_t* __restrict__ wpc,
    const float* __restrict__ b0, const float* __restrict__ b1,
    const float* __restrict__ bc,
    float* __restrict__ outp)
{
  __shared__ float sbuf[128*36];   // staging, then overwritten with c-values
  __shared__ float hbB[4*576];
  int tid = threadIdx.x;
  int s = blockA[blockIdx.x], e = blockA[blockIdx.x + 1];
  int n = e - s;
  if (n <= 0) return;
  if (n > 128) n = 128;   // maxcell << 64 so never hit

  for (int idx = tid; idx < n*8; idx += 256) {
    int r = idx >> 3, c = idx & 7;
    *(f32x4*)(sbuf + r*36 + c*4) =
      *(const f32x4*)(netin + ((size_t)(s + r))*32 + c*4);
  }
  __syncthreads();

  int wave = tid >> 6, lane = tid & 63;
  int m = lane & 15, q = lane >> 4;
  float* hb = hbB + wave*576;

  // read both chunks' xv BEFORE any sbuf overwrite
  int nch = (n + 63) >> 6;   // 1 or 2, block-uniform
  float xv[2][2][8];
#pragma unroll
  for (int c = 0; c < 2; c++) {
    if (c >= nch) break;
    int pt = s + c*64 + wave*16 + m;
    int pc = pt < e ? pt : (e-1);
    int row = pc - s;
    int g = gsort[pc];
    int cs = start[g] - s, ce = start[g+1] - s;
    const float* xr = sbuf + row*36 + q*8;
    *(f32x4*)&xv[c][0][0] = *(const f32x4*)xr;
    *(f32x4*)&xv[c][0][4] = *(const f32x4*)(xr + 4);
    f32x4 ma = (f32x4){-INFINITY,-INFINITY,-INFINITY,-INFINITY};
    f32x4 mb = ma;
    for (int k = cs; k < ce; k++) {
      const float* rr = sbuf + k*36 + q*8;
      f32x4 va = *(const f32x4*)rr;
      f32x4 vb = *(const f32x4*)(rr + 4);
      ma.x = fmaxf(ma.x, va.x); ma.y = fmaxf(ma.y, va.y);
      ma.z = fmaxf(ma.z, va.z); ma.w = fmaxf(ma.w, va.w);
      mb.x = fmaxf(mb.x, vb.x); mb.y = fmaxf(mb.y, vb.y);
      mb.z = fmaxf(mb.z, vb.z); mb.w = fmaxf(mb.w, vb.w);
    }
    *(f32x4*)&xv[c][1][0] = ma;
    *(f32x4*)&xv[c][1][4] = mb;
  }
  __syncthreads();   // all staging reads done; sbuf reusable

  bf16x8 w0f[2][2][2], wsf[2][2][2], w1f[2][2], wcf[2][2];
#pragma unroll
  for (int c = 0; c < 2; c++)
#pragma unroll
    for (int t = 0; t < 2; t++)
#pragma unroll
      for (int e2 = 0; e2 < 2; e2++) {
        w0f[c][t][e2] = *(const bf16x8*)(wp + ((size_t)(((c*2+t)*2+e2)    )*64 + lane)*8);
        wsf[c][t][e2] = *(const bf16x8*)(wp + ((size_t)(((c*2+t)*2+e2) + 8)*64 + lane)*8);
      }
#pragma unroll
  for (int t = 0; t < 2; t++)
#pragma unroll
    for (int e2 = 0; e2 < 2; e2++) {
      w1f[t][e2] = *(const bf16x8*)(wp  + ((size_t)(16 + t*2 + e2)*64 + lane)*8);
      wcf[t][e2] = *(const bf16x8*)(wpc + ((size_t)(     t*2 + e2)*64 + lane)*8);
    }

#pragma unroll
  for (int c = 0; c < 2; c++) {
    if (c >= nch) break;   // block-uniform
    bf16x8 axh[2], axl[2], arh[2], arl[2];
#pragma unroll
    for (int c2 = 0; c2 < 2; c2++) {
      float r[8];
#pragma unroll
      for (int j = 0; j < 8; j++) r[j] = fmaxf(xv[c][c2][j], 0.f);
      split8(xv[c][c2], axh[c2], axl[c2]);
      split8(r,         arh[c2], arl[c2]);
    }
    f32x4 hacc[2], yacc[2];
#pragma unroll
    for (int t = 0; t < 2; t++) {
      float bb0 = b0[m + 16*t], bb1 = b1[m + 16*t];
      hacc[t] = (f32x4){bb0,bb0,bb0,bb0};
      yacc[t] = (f32x4){bb1,bb1,bb1,bb1};
    }
#pragma unroll
    for (int c2 = 0; c2 < 2; c2++)
#pragma unroll
      for (int t = 0; t < 2; t++) {
        hacc[t] = MFMA16(arh[c2], w0f[c2][t][0], hacc[t]);
        hacc[t] = MFMA16(arl[c2], w0f[c2][t][0], hacc[t]);
        hacc[t] = MFMA16(arh[c2], w0f[c2][t][1], hacc[t]);
        yacc[t] = MFMA16(axh[c2], wsf[c2][t][0], yacc[t]);
        yacc[t] = MFMA16(axl[c2], wsf[c2][t][0], yacc[t]);
        yacc[t] = MFMA16(axh[c2], wsf[c2][t][1], yacc[t]);
      }
#pragma unroll
    for (int t = 0; t < 2; t++)
#pragma unroll
      for (int r = 0; r < 4; r++)
        hb[(q*4+r)*36 + m + 16*t] = fmaxf(hacc[t][r], 0.f);
    __syncthreads();
    float hv[8];
#pragma unroll
    for (int j = 0; j < 8; j++) hv[j] = hb[m*36 + q*8 + j];
    __syncthreads();
    bf16x8 hh, hl; split8(hv, hh, hl);
#pragma unroll
    for (int t = 0; t < 2; t++) {
      yacc[t] = MFMA16(hh, w1f[t][0], yacc[t]);
      yacc[t] = MFMA16(hl, w1f[t][0], yacc[t]);
      yacc[t] = MFMA16(hh, w1f[t][1], yacc[t]);
    }
    // y -> A-layout -> fc_c
#pragma unroll
    for (int t = 0; t < 2; t++)
#pragma unroll
      for (int r = 0; r < 4; r++)
        hb[(q*4+r)*36 + m + 16*t] = yacc[t][r];
    __syncthreads();
    float yv[8];
#pragma unroll
    for (int j = 0; j < 8; j++) yv[j] = hb[m*36 + q*8 + j];
    __syncthreads();
    bf16x8 yh, yl; split8(yv, yh, yl);
    f32x4 cacc[2];
#pragma unroll
    for (int t = 0; t < 2; t++) {
      float bb = bc[m + 16*t];
      cacc[t] = (f32x4){bb,bb,bb,bb};
      cacc[t] = MFMA16(yh, wcf[t][0], cacc[t]);
      cacc[t] = MFMA16(yl, wcf[t][0], cacc[t]);
      cacc[t] = MFMA16(yh, wcf[t][1], cacc[t]);
    }
#pragma unroll
    for (int t = 0; t < 2; t++)
#pragma unroll
      for (int r = 0; r < 4; r++) {
        int prow = c*64 + wave*16 + q*4 + r;
        if (prow < n) sbuf[prow*36 + m + 16*t] = cacc[t][r];
      }
    __syncthreads();
  }

  // mean per cell -> out (leaders = first point of cell)
  for (int r = tid; r < n; r += 256) {
    int pt = s + r;
    int g = gsort[pt];
    int gs = start[g];
    if (gs != pt) continue;
    int ge = start[g+1];
    float inv = 1.f / (float)(ge - gs);
    int b = g >> 15, cell = g & 32767;
    size_t ob = ((size_t)b << 20) + cell;
#pragma unroll
    for (int sub = 0; sub < 8; sub++) {
      f32x4 sm = (f32x4){0.f,0.f,0.f,0.f};
      for (int rr = gs - s; rr < ge - s; rr++) {
        f32x4 v = *(const f32x4*)(sbuf + rr*36 + sub*4);
        sm.x += v.x; sm.y += v.y; sm.z += v.z; sm.w += v.w;
      }
#pragma unroll
      for (int j = 0; j < 4; j++)
        outp[ob + ((size_t)(sub*4 + j) << 15)] = ((float*)&sm)[j] * inv;
    }
  }
}

extern "C" void kernel_launch(void* const* d_in, const int* in_sizes, int n_in,
                              void* d_out, int out_size, void* d_ws, size_t ws_size,
                              hipStream_t stream)
{
  const float* p   = (const float*)d_in[0];
  const float* Wp  = (const float*)d_in[1];
  const float* bp  = (const float*)d_in[2];
  const float* f0w = (const float*)d_in[3];
  const float* f0b = (const float*)d_in[4];
  const float* f1w = (const float*)d_in[5];
  const float* f1b = (const float*)d_in[6];
  const float* scw = (const float*)d_in[7];
  const float* wc  = (const float*)d_in[8];
  const float* bc  = (const float*)d_in[9];
  float* outp = (float*)d_out;

  char* wsb = (char*)d_ws;
  float*    netA     = (float*)wsb;                       // NPTS*32 f32
  float*    netB     = netA + (size_t)NPTS*32;            // NPTS*32 f32
  int*      gbuf     = (int*)(netB + (size_t)NPTS*32);    // NPTS
  int*      gsort    = gbuf + NPTS;                       // NPTS
  int*      hist     = gsort + NPTS;                      // BG
  int*      start    = hist + BG;                         // BG+1
  int*      cursor   = start + BG + 1;                    // BG
  int*      texcl    = cursor + BG;                       // BG
  int*      bsum     = texcl + BG;                        // 256
  int*      boff     = bsum + 256;                        // 256
  int*      blockA   = boff + 256;                        // NMEGA+1
  ushort_t* wpack    = (ushort_t*)(blockA + NMEGA + 1);   // 120*512 ushort
  float*    p_sorted = (float*)(wpack + (size_t)120*512); // NPTS*3

  dim3 blk(256);
  dim3 gpts((NPTS + 255)/256);
  dim3 gmfma(NPTS/64);
  dim3 gscan(BG/256);

  hipMemsetAsync(hist, 0, (size_t)BG*4, stream);
  hipMemsetAsync(outp, 0, (size_t)out_size*sizeof(float), stream);
  hipLaunchKernelGGL(k_hist, gpts, blk, 0, stream, p, gbuf, hist);
  hipLaunchKernelGGL(k_scanA, gscan, blk, 0, stream, hist, texcl, bsum);
  hipLaunchKernelGGL(k_scanB, dim3(1), blk, 0, stream, bsum, boff);
  hipLaunchKernelGGL(k_scanC, gscan, blk, 0, stream, texcl, boff, start, cursor);
  hipLaunchKernelGGL(k_scatter, gpts, blk, 0, stream, p, gbuf, cursor, p_sorted, gsort);
  hipLaunchKernelGGL(k_blocks, dim3((NMEGA + 256)/256), blk, 0, stream, start, blockA);
  hipLaunchKernelGGL(k_pack, dim3(120), dim3(64), 0, stream, f0w, scw, f1w, wc, Wp, wpack);
  hipLaunchKernelGGL(k_fused0, gmfma, blk, 0, stream,
                     p_sorted, wpack + (size_t)104*512, bp,
                     wpack + (size_t)0*20*512, f0b + 0*32, f1b + 0*32, netA);
  hipLaunchKernelGGL(k_stage_f, gmfma, blk, 0, stream, netA, netB, gsort, start,
                     wpack + (size_t)1*20*512, f0b + 1*32, f1b + 1*32);
  hipLaunchKernelGGL(k_stage_f, gmfma, blk, 0, stream, netB, netA, gsort, start,
                     wpack + (size_t)2*20*512, f0b + 2*32, f1b + 2*32);
  hipLaunchKernelGGL(k_stage_f, gmfma, blk, 0, stream, netA, netB, gsort, start,
                     wpack + (size_t)3*20*512, f0b + 3*32, f1b + 3*32);
  hipLaunchKernelGGL(k_finalmean, dim3(NMEGA), blk, 0, stream, netB, gsort, start, blockA,
                     wpack + (size_t)4*20*512, wpack + (size_t)100*512,
                     f0b + 4*32, f1b + 4*32, bc, outp);
}